// Round 4
// baseline (162.291 us; speedup 1.0000x reference)
//
#include <hip/hip_runtime.h>

// Problem constants (B, L, H, HS, OUT) = (4, 512, 768, 64, 16)
#define Bc   4
#define Lc   512
#define Hc   768
#define HSc  64
#define OUTc 16
#define Pc   131328   // L*(L+1)/2
#define NTOK 2048     // B*L
#define XPITCH 776    // 768 + 8 bf16 pad -> 16B-aligned rows, banks spread

typedef float  floatx4 __attribute__((ext_vector_type(4)));
typedef short  bf16x8  __attribute__((ext_vector_type(8)));   // 8 bf16 in 4 VGPRs
typedef float  f32x4   __attribute__((ext_vector_type(4)));

// ws layout (floats): q@0 [131072], k@131072 [131072], A@262144 [32768],
//                     Eq@294912 [32768], Ek@327680 [32768], flags@360448 [256 u32]

__device__ __forceinline__ unsigned short f2bf(float f) {
    unsigned int u = __float_as_uint(f);
    return (unsigned short)((u + 0x7FFFu + ((u >> 16) & 1u)) >> 16);   // RNE
}

// Single kernel, flag-based producer/consumer (no cooperative API).
// Blocks 0..255: phase 1 = prep + QK-GEMM + A/Eq/Ek projection (bit-identical
// to the R2 qkae_kernel), then release-publish flags[bx]=1.
// All 576 blocks: phase 2 = pair assembly for tile bx (bit-identical to R2
// pair_kernel), gated on the 9 producer flags the tile actually needs:
//   q/A of s-rows  -> flag 2*(b*32+i)
//   Eq of e-rows   -> flags 2*(b*32+j*4+t), t=0..3
//   k/Ek of e-rows -> flags 2*(b*32+j*4+t)+1
// Early tiles start streaming stores while late GEMM blocks still run.
// Deadlock-free: LDS 37120 B -> 4 blk/CU, launch_bounds(256,3) -> >=3 blk/CU
// => all 576 blocks co-resident (cap >= 768).
__global__ __launch_bounds__(256, 3) void fused_kernel(
    const float* __restrict__ x, const float* __restrict__ Wq,
    const float* __restrict__ Wk, const float* __restrict__ bq,
    const float* __restrict__ bk, const float* __restrict__ Wb,
    const float* __restrict__ bb,
    float* __restrict__ qws, float* __restrict__ kws,
    float* __restrict__ Aws, float* __restrict__ Eqws,
    float* __restrict__ Ekws, unsigned* __restrict__ flags,
    float* __restrict__ out)
{
    __shared__ alignas(16) unsigned char smem[37120];
    const int tid = threadIdx.x;
    const int bx  = blockIdx.x;

    // ---------------- Phase 1: QK GEMM + projections (blocks 0..255) -------
    if (bx < 256) {
        unsigned short* xs  = (unsigned short*)smem;          // 16 x XPITCH bf16
        float*          lw0 = (float*)(smem + 24832);         // 64x16
        float*          lw1 = (float*)(smem + 28928);         // 64x16
        float*          lqk = (float*)(smem + 33024);         // 16x64

        const int mb   = bx >> 1;
        const int half = bx & 1;           // 0 = q, 1 = k
        const int m0   = mb * 16;

        // stage Wb slices (1024 floats each)
        if (half == 0) {
            #pragma unroll
            for (int i = 0; i < 4; ++i) {
                lw0[tid + i * 256] = Wb[tid + i * 256];           // rows 0..63   (A)
                lw1[tid + i * 256] = Wb[2048 + tid + i * 256];    // rows 128..191(Eq)
            }
        } else {
            #pragma unroll
            for (int i = 0; i < 4; ++i) {                          // rows 64..127 + 192..255
                lw0[tid + i * 256] = Wb[1024 + tid + i * 256] + Wb[3072 + tid + i * 256];
            }
        }

        // stage x tile as bf16 into padded LDS rows (3072 float4 total)
        {
            const float4* xg = (const float4*)(x + (size_t)m0 * Hc);
            #pragma unroll
            for (int i = 0; i < 12; ++i) {
                const int idx = tid + i * 256;
                const int r   = idx / 192;           // row 0..15
                const int c4  = idx - r * 192;       // float4 col 0..191
                const float4 v = xg[idx];
                *(ushort4*)(xs + r * XPITCH + c4 * 4) =
                    make_ushort4(f2bf(v.x), f2bf(v.y), f2bf(v.z), f2bf(v.w));
            }
        }
        __syncthreads();

        const int w    = tid >> 6;
        const int lane = tid & 63;
        const int l15  = lane & 15;
        const int quad = lane >> 4;
        const int nq   = w * 16 + l15;           // output col 0..63 within this half

        const float* bsrc = half ? Wk : Wq;
        const unsigned short* ap = xs + l15 * XPITCH + quad * 8;

        f32x4 acc = {0.f, 0.f, 0.f, 0.f};
        #pragma unroll 4
        for (int k0 = 0; k0 < Hc; k0 += 32) {
            const bf16x8 af = *(const bf16x8*)(ap + k0);       // ds_read_b128
            const int kb = k0 + quad * 8;
            bf16x8 bf;
            #pragma unroll
            for (int j = 0; j < 8; ++j)                        // quad-coalesced dwords
                bf[j] = (short)f2bf(bsrc[(kb + j) * HSc + nq]);
            acc = __builtin_amdgcn_mfma_f32_16x16x32_bf16(af, bf, acc, 0, 0, 0);
        }

        const float bias = half ? bk[nq] : bq[nq];
        float* dst = half ? kws : qws;
        #pragma unroll
        for (int r = 0; r < 4; ++r) {
            const int t = quad * 4 + r;
            const float v = acc[r] + bias;
            dst[(size_t)(m0 + t) * HSc + nq] = v;
            lqk[t * 64 + nq] = v;
        }
        __syncthreads();

        // projection epilogue: 16 threads per token, one output col each
        const int t   = tid >> 4;        // token 0..15
        const int c   = tid & 15;
        const int tok = m0 + t;
        const float* row = lqk + t * 64;
        if (half == 0) {
            float a = 0.f, eq = 0.f;
            #pragma unroll 8
            for (int h = 0; h < 64; ++h) {
                const float rv = row[h];
                a  += rv * lw0[h * OUTc + c];
                eq += rv * lw1[h * OUTc + c];
            }
            Aws[(size_t)tok * OUTc + c]  = a;
            Eqws[(size_t)tok * OUTc + c] = eq;
        } else {
            float ek = bb[c];
            #pragma unroll 8
            for (int h = 0; h < 64; ++h)
                ek += row[h] * lw0[h * OUTc + c];
            Ekws[(size_t)tok * OUTc + c] = ek;
        }

        // publish: all stores -> agent scope, then set flag (release)
        __threadfence();
        __syncthreads();
        if (tid == 0)
            __hip_atomic_store(&flags[bx], 1u, __ATOMIC_RELEASE,
                               __HIP_MEMORY_SCOPE_AGENT);
    }

    // ---------------- Phase 2: pair assembly (all 576 blocks) --------------
    {
        float* q_tile = (float*)smem;            // [16][64]
        float* A_tile = (float*)(smem + 4096);   // [16][16]

        // decode: tile id 0..143 within batch, j >= i>>2 upper-triangular
        int n = bx % 144;
        const int b = bx / 144;
        int g = 0;
        int cnt = 32;                       // 4*(8-g)
        while (n >= cnt) { n -= cnt; ++g; cnt = 4 * (8 - g); }
        const int span = 8 - g;
        const int i = g * 4 + n / span;
        const int j = g + n % span;

        const int s0 = i * 16;
        const int e0 = j * 64;

        // wait for the 9 producers this tile depends on
        {
            const int base = b * 32 + j * 4;
            if (tid < 9) {
                int pid;
                if (tid == 0) pid = 2 * (b * 32 + i);              // q/A of s-rows
                else {
                    const int t = (tid - 1) & 3;
                    pid = 2 * (base + t) + ((tid - 1) >> 2);       // Eq then k/Ek
                }
                while (!__hip_atomic_load(&flags[pid], __ATOMIC_ACQUIRE,
                                          __HIP_MEMORY_SCOPE_AGENT))
                    __builtin_amdgcn_s_sleep(2);
            }
            __syncthreads();
        }

        {
            const int r = tid >> 4, c4 = tid & 15;
            ((float4*)(q_tile + r * 64))[c4] =
                ((const float4*)(qws + ((size_t)b * Lc + s0 + r) * HSc))[c4];
            if (tid < 64) {
                const int ra = tid >> 2, ca = tid & 3;
                ((float4*)(A_tile + ra * 16))[ca] =
                    ((const float4*)(Aws + ((size_t)b * Lc + s0 + ra) * OUTc))[ca];
            }
        }
        __syncthreads();

        const int gidx = tid >> 2;
        const int l = tid & 3;
        const int e = e0 + gidx;

        const float4* kk = (const float4*)(kws + ((size_t)b * Lc + e) * HSc);
        const float4 kv0 = kk[l];
        const float4 kv1 = kk[4 + l];
        const float4 kv2 = kk[8 + l];
        const float4 kv3 = kk[12 + l];
        const float4 evq = ((const float4*)(Eqws + ((size_t)b * Lc + e) * OUTc))[l];
        const float4 evk = ((const float4*)(Ekws + ((size_t)b * Lc + e) * OUTc))[l];
        const float4 ev  = make_float4(evq.x + evk.x, evq.y + evk.y,
                                       evq.z + evk.z, evq.w + evk.w);

        float* ob = out + (size_t)b * Pc * OUTc;

        #pragma unroll 8
        for (int sl = 0; sl < 16; ++sl) {
            const int s = s0 + sl;
            const float4* qq = (const float4*)(q_tile + sl * 64);
            const float4 qv0 = qq[l];
            const float4 qv1 = qq[4 + l];
            const float4 qv2 = qq[8 + l];
            const float4 qv3 = qq[12 + l];

            float sc = qv0.x * kv0.x + qv0.y * kv0.y + qv0.z * kv0.z + qv0.w * kv0.w
                     + qv1.x * kv1.x + qv1.y * kv1.y + qv1.z * kv1.z + qv1.w * kv1.w
                     + qv2.x * kv2.x + qv2.y * kv2.y + qv2.z * kv2.z + qv2.w * kv2.w
                     + qv3.x * kv3.x + qv3.y * kv3.y + qv3.z * kv3.z + qv3.w * kv3.w;
            sc += __shfl_xor(sc, 1);
            sc += __shfl_xor(sc, 2);

            if (e >= s) {
                const float4 av = ((const float4*)(A_tile + sl * 16))[l];
                const int row = s * (2 * Lc + 1 - s) / 2 + (e - s);
                floatx4 r;
                r.x = av.x + ev.x + sc;
                r.y = av.y + ev.y + sc;
                r.z = av.z + ev.z + sc;
                r.w = av.w + ev.w + sc;
                __builtin_nontemporal_store(r, (floatx4*)(ob + (size_t)row * OUTc) + l);
            }
        }
    }
}

extern "C" void kernel_launch(void* const* d_in, const int* in_sizes, int n_in,
                              void* d_out, int out_size, void* d_ws, size_t ws_size,
                              hipStream_t stream) {
    const float* x  = (const float*)d_in[0];
    const float* Wq = (const float*)d_in[1];
    const float* bq = (const float*)d_in[2];
    const float* Wk = (const float*)d_in[3];
    const float* bk = (const float*)d_in[4];
    const float* Wb = (const float*)d_in[5];
    const float* bb = (const float*)d_in[6];

    float* ws   = (float*)d_ws;
    float* qws  = ws;
    float* kws  = ws + 131072;
    float* Aws  = ws + 262144;
    float* Eqws = ws + 294912;
    float* Ekws = ws + 327680;
    unsigned* flags = (unsigned*)(ws + 360448);

    hipMemsetAsync(flags, 0, 256 * sizeof(unsigned), stream);
    fused_kernel<<<dim3(576), dim3(256), 0, stream>>>(
        x, Wq, Wk, bq, bk, Wb, bb, qws, kws, Aws, Eqws, Ekws, flags,
        (float*)d_out);
}

// Round 5
// 119.444 us; speedup vs baseline: 1.3587x; 1.3587x over previous
//
#include <hip/hip_runtime.h>

// Problem constants (B, L, H, HS, OUT) = (4, 512, 768, 64, 16)
#define Bc   4
#define Lc   512
#define Hc   768
#define HSc  64
#define OUTc 16
#define Pc   131328   // L*(L+1)/2
#define NTOK 2048     // B*L
#define XPITCH 776    // 768 + 8 bf16 pad -> 16B-aligned rows, banks spread

typedef float  floatx4 __attribute__((ext_vector_type(4)));
typedef short  bf16x8  __attribute__((ext_vector_type(8)));   // 8 bf16 in 4 VGPRs
typedef float  f32x4   __attribute__((ext_vector_type(4)));

// ws layout (floats): q@0 [131072], k@131072 [131072], A@262144 [32768],
//                     Eq@294912 [32768], Ek@327680 [32768], flags@360448 [256 u32]

__device__ __forceinline__ unsigned short f2bf(float f) {
    unsigned int u = __float_as_uint(f);
    return (unsigned short)((u + 0x7FFFu + ((u >> 16) & 1u)) >> 16);   // RNE
}

// Single kernel, flag-based producer/consumer (no cooperative API).
// Blocks 0..255: phase 1 = prep + QK-GEMM + A/Eq/Ek projection, then
// release-publish flags[bx]=1. All 576 blocks: phase 2 = pair assembly,
// gated on the 9 producer flags the tile needs.
// R4 lesson: polling with ACQUIRE@AGENT emits a cache invalidate PER POLL ->
// XCD-wide L2 invalidate storm while phase 1 runs (116 us kernel). Fix: spin
// on RELAXED loads (no invalidate, reads coherent point), then ONE acquire
// load after the flag is seen -- same release/acquire edge, 1 inv per block.
// Deadlock-free: LDS 37376 B -> 4 blk/CU, launch_bounds(256,3) -> >=3 blk/CU
// => all 576 blocks co-resident (cap >= 768).
__global__ __launch_bounds__(256, 3) void fused_kernel(
    const float* __restrict__ x, const float* __restrict__ Wq,
    const float* __restrict__ Wk, const float* __restrict__ bq,
    const float* __restrict__ bk, const float* __restrict__ Wb,
    const float* __restrict__ bb,
    float* __restrict__ qws, float* __restrict__ kws,
    float* __restrict__ Aws, float* __restrict__ Eqws,
    float* __restrict__ Ekws, unsigned* __restrict__ flags,
    float* __restrict__ out)
{
    __shared__ alignas(16) unsigned char smem[37120];
    const int tid = threadIdx.x;
    const int bx  = blockIdx.x;

    // ---------------- Phase 1: QK GEMM + projections (blocks 0..255) -------
    if (bx < 256) {
        unsigned short* xs  = (unsigned short*)smem;          // 16 x XPITCH bf16
        float*          lw0 = (float*)(smem + 24832);         // 64x16
        float*          lw1 = (float*)(smem + 28928);         // 64x16
        float*          lqk = (float*)(smem + 33024);         // 16x64

        const int mb   = bx >> 1;
        const int half = bx & 1;           // 0 = q, 1 = k
        const int m0   = mb * 16;

        // stage Wb slices (1024 floats each)
        if (half == 0) {
            #pragma unroll
            for (int i = 0; i < 4; ++i) {
                lw0[tid + i * 256] = Wb[tid + i * 256];           // rows 0..63   (A)
                lw1[tid + i * 256] = Wb[2048 + tid + i * 256];    // rows 128..191(Eq)
            }
        } else {
            #pragma unroll
            for (int i = 0; i < 4; ++i) {                          // rows 64..127 + 192..255
                lw0[tid + i * 256] = Wb[1024 + tid + i * 256] + Wb[3072 + tid + i * 256];
            }
        }

        // stage x tile as bf16 into padded LDS rows (3072 float4 total)
        {
            const float4* xg = (const float4*)(x + (size_t)m0 * Hc);
            #pragma unroll
            for (int i = 0; i < 12; ++i) {
                const int idx = tid + i * 256;
                const int r   = idx / 192;           // row 0..15
                const int c4  = idx - r * 192;       // float4 col 0..191
                const float4 v = xg[idx];
                *(ushort4*)(xs + r * XPITCH + c4 * 4) =
                    make_ushort4(f2bf(v.x), f2bf(v.y), f2bf(v.z), f2bf(v.w));
            }
        }
        __syncthreads();

        const int w    = tid >> 6;
        const int lane = tid & 63;
        const int l15  = lane & 15;
        const int quad = lane >> 4;
        const int nq   = w * 16 + l15;           // output col 0..63 within this half

        const float* bsrc = half ? Wk : Wq;
        const unsigned short* ap = xs + l15 * XPITCH + quad * 8;

        f32x4 acc = {0.f, 0.f, 0.f, 0.f};
        #pragma unroll 4
        for (int k0 = 0; k0 < Hc; k0 += 32) {
            const bf16x8 af = *(const bf16x8*)(ap + k0);       // ds_read_b128
            const int kb = k0 + quad * 8;
            bf16x8 bf;
            #pragma unroll
            for (int j = 0; j < 8; ++j)                        // quad-coalesced dwords
                bf[j] = (short)f2bf(bsrc[(kb + j) * HSc + nq]);
            acc = __builtin_amdgcn_mfma_f32_16x16x32_bf16(af, bf, acc, 0, 0, 0);
        }

        const float bias = half ? bk[nq] : bq[nq];
        float* dst = half ? kws : qws;
        #pragma unroll
        for (int r = 0; r < 4; ++r) {
            const int t = quad * 4 + r;
            const float v = acc[r] + bias;
            dst[(size_t)(m0 + t) * HSc + nq] = v;
            lqk[t * 64 + nq] = v;
        }
        __syncthreads();

        // projection epilogue: 16 threads per token, one output col each
        const int t   = tid >> 4;        // token 0..15
        const int c   = tid & 15;
        const int tok = m0 + t;
        const float* row = lqk + t * 64;
        if (half == 0) {
            float a = 0.f, eq = 0.f;
            #pragma unroll 8
            for (int h = 0; h < 64; ++h) {
                const float rv = row[h];
                a  += rv * lw0[h * OUTc + c];
                eq += rv * lw1[h * OUTc + c];
            }
            Aws[(size_t)tok * OUTc + c]  = a;
            Eqws[(size_t)tok * OUTc + c] = eq;
        } else {
            float ek = bb[c];
            #pragma unroll 8
            for (int h = 0; h < 64; ++h)
                ek += row[h] * lw0[h * OUTc + c];
            Ekws[(size_t)tok * OUTc + c] = ek;
        }

        // publish: all stores -> agent scope, then set flag (release)
        __threadfence();
        __syncthreads();
        if (tid == 0)
            __hip_atomic_store(&flags[bx], 1u, __ATOMIC_RELEASE,
                               __HIP_MEMORY_SCOPE_AGENT);
    }

    // ---------------- Phase 2: pair assembly (all 576 blocks) --------------
    {
        float* q_tile = (float*)smem;            // [16][64]
        float* A_tile = (float*)(smem + 4096);   // [16][16]

        // decode: tile id 0..143 within batch, j >= i>>2 upper-triangular
        int n = bx % 144;
        const int b = bx / 144;
        int g = 0;
        int cnt = 32;                       // 4*(8-g)
        while (n >= cnt) { n -= cnt; ++g; cnt = 4 * (8 - g); }
        const int span = 8 - g;
        const int i = g * 4 + n / span;
        const int j = g + n % span;

        const int s0 = i * 16;
        const int e0 = j * 64;

        // wait for the 9 producers this tile depends on: RELAXED spin
        // (no invalidate per poll), then ONE acquire load to pair with the
        // producer's release store.
        {
            const int base = b * 32 + j * 4;
            if (tid < 9) {
                int pid;
                if (tid == 0) pid = 2 * (b * 32 + i);              // q/A of s-rows
                else {
                    const int t = (tid - 1) & 3;
                    pid = 2 * (base + t) + ((tid - 1) >> 2);       // Eq then k/Ek
                }
                while (!__hip_atomic_load(&flags[pid], __ATOMIC_RELAXED,
                                          __HIP_MEMORY_SCOPE_AGENT))
                    __builtin_amdgcn_s_sleep(8);
                (void)__hip_atomic_load(&flags[pid], __ATOMIC_ACQUIRE,
                                        __HIP_MEMORY_SCOPE_AGENT);
            }
            __syncthreads();
        }

        {
            const int r = tid >> 4, c4 = tid & 15;
            ((float4*)(q_tile + r * 64))[c4] =
                ((const float4*)(qws + ((size_t)b * Lc + s0 + r) * HSc))[c4];
            if (tid < 64) {
                const int ra = tid >> 2, ca = tid & 3;
                ((float4*)(A_tile + ra * 16))[ca] =
                    ((const float4*)(Aws + ((size_t)b * Lc + s0 + ra) * OUTc))[ca];
            }
        }
        __syncthreads();

        const int gidx = tid >> 2;
        const int l = tid & 3;
        const int e = e0 + gidx;

        const float4* kk = (const float4*)(kws + ((size_t)b * Lc + e) * HSc);
        const float4 kv0 = kk[l];
        const float4 kv1 = kk[4 + l];
        const float4 kv2 = kk[8 + l];
        const float4 kv3 = kk[12 + l];
        const float4 evq = ((const float4*)(Eqws + ((size_t)b * Lc + e) * OUTc))[l];
        const float4 evk = ((const float4*)(Ekws + ((size_t)b * Lc + e) * OUTc))[l];
        const float4 ev  = make_float4(evq.x + evk.x, evq.y + evk.y,
                                       evq.z + evk.z, evq.w + evk.w);

        float* ob = out + (size_t)b * Pc * OUTc;

        #pragma unroll 8
        for (int sl = 0; sl < 16; ++sl) {
            const int s = s0 + sl;
            const float4* qq = (const float4*)(q_tile + sl * 64);
            const float4 qv0 = qq[l];
            const float4 qv1 = qq[4 + l];
            const float4 qv2 = qq[8 + l];
            const float4 qv3 = qq[12 + l];

            float sc = qv0.x * kv0.x + qv0.y * kv0.y + qv0.z * kv0.z + qv0.w * kv0.w
                     + qv1.x * kv1.x + qv1.y * kv1.y + qv1.z * kv1.z + qv1.w * kv1.w
                     + qv2.x * kv2.x + qv2.y * kv2.y + qv2.z * kv2.z + qv2.w * kv2.w
                     + qv3.x * kv3.x + qv3.y * kv3.y + qv3.z * kv3.z + qv3.w * kv3.w;
            sc += __shfl_xor(sc, 1);
            sc += __shfl_xor(sc, 2);

            if (e >= s) {
                const float4 av = ((const float4*)(A_tile + sl * 16))[l];
                const int row = s * (2 * Lc + 1 - s) / 2 + (e - s);
                floatx4 r;
                r.x = av.x + ev.x + sc;
                r.y = av.y + ev.y + sc;
                r.z = av.z + ev.z + sc;
                r.w = av.w + ev.w + sc;
                __builtin_nontemporal_store(r, (floatx4*)(ob + (size_t)row * OUTc) + l);
            }
        }
    }
}

extern "C" void kernel_launch(void* const* d_in, const int* in_sizes, int n_in,
                              void* d_out, int out_size, void* d_ws, size_t ws_size,
                              hipStream_t stream) {
    const float* x  = (const float*)d_in[0];
    const float* Wq = (const float*)d_in[1];
    const float* bq = (const float*)d_in[2];
    const float* Wk = (const float*)d_in[3];
    const float* bk = (const float*)d_in[4];
    const float* Wb = (const float*)d_in[5];
    const float* bb = (const float*)d_in[6];

    float* ws   = (float*)d_ws;
    float* qws  = ws;
    float* kws  = ws + 131072;
    float* Aws  = ws + 262144;
    float* Eqws = ws + 294912;
    float* Ekws = ws + 327680;
    unsigned* flags = (unsigned*)(ws + 360448);

    hipMemsetAsync(flags, 0, 256 * sizeof(unsigned), stream);
    fused_kernel<<<dim3(576), dim3(256), 0, stream>>>(
        x, Wq, Wk, bq, bk, Wb, bb, qws, kws, Aws, Eqws, Ekws, flags,
        (float*)d_out);
}

// Round 6
// 94.239 us; speedup vs baseline: 1.7221x; 1.2675x over previous
//
#include <hip/hip_runtime.h>

// Problem constants (B, L, H, HS, OUT) = (4, 512, 768, 64, 16)
#define Bc   4
#define Lc   512
#define Hc   768
#define HSc  64
#define OUTc 16
#define Pc   131328   // L*(L+1)/2
#define NTOK 2048     // B*L
#define XPITCH 776    // 768 + 8 bf16 pad -> 16B-aligned rows, banks spread

typedef float  floatx4 __attribute__((ext_vector_type(4)));
typedef short  bf16x8  __attribute__((ext_vector_type(8)));   // 8 bf16 in 4 VGPRs
typedef float  f32x4   __attribute__((ext_vector_type(4)));

// ws layout (floats): q@0 [131072], k@131072 [131072], A@262144 [32768],
//                     Eq@294912 [32768], Ek@327680 [32768]

__device__ __forceinline__ unsigned short f2bf(float f) {
    unsigned int u = __float_as_uint(f);
    return (unsigned short)((u + 0x7FFFu + ((u >> 16) & 1u)) >> 16);   // RNE
}

// Fused prep + QK-GEMM + A/E projection (two-kernel structure restored; the
// R4/R5 single-kernel fusion lost ~30 us to intra-kernel cross-XCD sync).
// Grid 256 x 256 thr (4 waves). Block bx: mb = bx>>1 (16-token tile),
// half = bx&1 (0 = q side, 1 = k side).
// R5 lesson: the old in-register W path (192 scalar dword loads / lane,
// 1 wave/SIMD) was latency-bound and dominated the kernel. Now W is staged
// through LDS in 3 K-chunks of 256: wave-coalesced 256B dword loads ->
// f2bf -> ds_write_b64, XOR-swizzled (ushort off = k ^ ((n&15)<<3)) so the
// b64 writes are 2-way (free) and the b128 B-fragment reads are at the
// structural minimum (conflict-free). MFMA reads both operands via
// ds_read_b128. Numerics identical to R2 (same f2bf RNE, same MFMA order).
// MFMA layouts (m89/m91): A[m=lane&15][k=quad*8+j]; B[k=quad*8+j][n=lane&15];
// D: col=lane&15, row=quad*4+reg.
__global__ __launch_bounds__(256) void qkae_kernel(
    const float* __restrict__ x, const float* __restrict__ Wq,
    const float* __restrict__ Wk, const float* __restrict__ bq,
    const float* __restrict__ bk, const float* __restrict__ Wb,
    const float* __restrict__ bb,
    float* __restrict__ qws, float* __restrict__ kws,
    float* __restrict__ Aws, float* __restrict__ Eqws,
    float* __restrict__ Ekws)
{
    __shared__ alignas(16) unsigned short xs[16 * XPITCH];  // 24832 B
    __shared__ alignas(16) unsigned short Wl[64 * 256];     // 32768 B, swizzled
    __shared__ float lw0[64 * OUTc];                        // 4 KB
    __shared__ float lw1[64 * OUTc];                        // 4 KB
    __shared__ float lqk[16][64];                           // 4 KB

    const int tid  = threadIdx.x;
    const int mb   = blockIdx.x >> 1;
    const int half = blockIdx.x & 1;       // 0 = q, 1 = k
    const int m0   = mb * 16;

    // stage Wb slices (1024 floats each)
    if (half == 0) {
        #pragma unroll
        for (int i = 0; i < 4; ++i) {
            lw0[tid + i * 256] = Wb[tid + i * 256];           // rows 0..63   (A)
            lw1[tid + i * 256] = Wb[2048 + tid + i * 256];    // rows 128..191(Eq)
        }
    } else {
        #pragma unroll
        for (int i = 0; i < 4; ++i) {                          // rows 64..127 + 192..255
            lw0[tid + i * 256] = Wb[1024 + tid + i * 256] + Wb[3072 + tid + i * 256];
        }
    }

    // stage x tile as bf16 into padded LDS rows (3072 float4 total)
    {
        const float4* xg = (const float4*)(x + (size_t)m0 * Hc);
        #pragma unroll
        for (int i = 0; i < 12; ++i) {
            const int idx = tid + i * 256;
            const int r   = idx / 192;           // row 0..15
            const int c4  = idx - r * 192;       // float4 col 0..191
            const float4 v = xg[idx];
            *(ushort4*)(xs + r * XPITCH + c4 * 4) =
                make_ushort4(f2bf(v.x), f2bf(v.y), f2bf(v.z), f2bf(v.w));
        }
    }

    const int w    = tid >> 6;
    const int lane = tid & 63;
    const int l15  = lane & 15;
    const int quad = lane >> 4;
    const int nq   = w * 16 + l15;           // output col 0..63 within this half

    const float* bsrc = half ? Wk : Wq;
    const unsigned short* ap = xs + l15 * XPITCH + quad * 8;

    // W staging lane roles: row n = lane (0..63), wave w covers k%16 = w*4..w*4+3
    const int nrow = lane;
    const int swzw = (nrow & 15) << 3;       // write-side XOR (ushort units)
    const int swzr = l15 << 3;               // read-side XOR for row nq (nq&15 = l15)

    f32x4 acc = {0.f, 0.f, 0.f, 0.f};
    #pragma unroll
    for (int kc = 0; kc < 3; ++kc) {
        // stage chunk kc: Wl[n][k] = bf16(W[kc*256+k][n]), k in [0,256)
        #pragma unroll 4
        for (int kb = 0; kb < 16; ++kb) {
            const int kl = kb * 16 + w * 4;          // k within chunk
            const int kg = kc * 256 + kl;            // global k
            ushort4 o;
            o.x = f2bf(bsrc[(kg + 0) * HSc + nrow]);
            o.y = f2bf(bsrc[(kg + 1) * HSc + nrow]);
            o.z = f2bf(bsrc[(kg + 2) * HSc + nrow]);
            o.w = f2bf(bsrc[(kg + 3) * HSc + nrow]);
            *(ushort4*)(Wl + nrow * 256 + (kl ^ swzw)) = o;
        }
        __syncthreads();
        #pragma unroll
        for (int it = 0; it < 8; ++it) {
            const bf16x8 a = *(const bf16x8*)(ap + kc * 256 + it * 32);
            const int kl = it * 32 + quad * 8;
            const bf16x8 b = *(const bf16x8*)(Wl + nq * 256 + (kl ^ swzr));
            acc = __builtin_amdgcn_mfma_f32_16x16x32_bf16(a, b, acc, 0, 0, 0);
        }
        __syncthreads();
    }

    const float bias = half ? bk[nq] : bq[nq];
    float* dst = half ? kws : qws;
    #pragma unroll
    for (int r = 0; r < 4; ++r) {
        const int t = quad * 4 + r;
        const float v = acc[r] + bias;
        dst[(size_t)(m0 + t) * HSc + nq] = v;
        lqk[t][nq] = v;
    }
    __syncthreads();

    // projection epilogue: 16 threads per token, one output col each
    const int t   = tid >> 4;        // token 0..15
    const int c   = tid & 15;
    const int tok = m0 + t;
    const float* row = lqk[t];
    if (half == 0) {
        float a = 0.f, eq = 0.f;
        #pragma unroll 8
        for (int h = 0; h < 64; ++h) {
            const float rv = row[h];
            a  += rv * lw0[h * OUTc + c];
            eq += rv * lw1[h * OUTc + c];
        }
        Aws[(size_t)tok * OUTc + c]  = a;
        Eqws[(size_t)tok * OUTc + c] = eq;
    } else {
        float ek = bb[c];
        #pragma unroll 8
        for (int h = 0; h < 64; ++h)
            ek += row[h] * lw0[h * OUTc + c];
        Ekws[(size_t)tok * OUTc + c] = ek;
    }
}

// Pair kernel: 16 s x 64 e tiles, only the 144 active upper-triangular tiles
// per batch (decoded in-kernel). Grid (144, 4): x = linear tile id, y = batch.
__global__ __launch_bounds__(256) void pair_kernel(
    const float* __restrict__ qws, const float* __restrict__ kws,
    const float* __restrict__ Aws, const float* __restrict__ Eqws,
    const float* __restrict__ Ekws,
    float* __restrict__ out)
{
    // decode linear tile id -> (i = s-tile 0..31, j = e-tile 0..7), j >= i>>2
    int n = blockIdx.x;
    int g = 0;
    int cnt = 32;                       // 4*(8-g)
    while (n >= cnt) { n -= cnt; ++g; cnt = 4 * (8 - g); }
    const int span = 8 - g;
    const int i = g * 4 + n / span;
    const int j = g + n % span;
    const int b = blockIdx.y;

    __shared__ alignas(16) float q_tile[16][64];
    __shared__ alignas(16) float A_tile[16][16];

    const int tid = threadIdx.x;
    const int s0 = i * 16;
    const int e0 = j * 64;

    {
        const int r = tid >> 4, c4 = tid & 15;
        ((float4*)q_tile[r])[c4] =
            ((const float4*)(qws + ((size_t)b * Lc + s0 + r) * HSc))[c4];
        if (tid < 64) {
            const int ra = tid >> 2, ca = tid & 3;
            ((float4*)A_tile[ra])[ca] =
                ((const float4*)(Aws + ((size_t)b * Lc + s0 + ra) * OUTc))[ca];
        }
    }
    __syncthreads();

    const int gidx = tid >> 2;
    const int l = tid & 3;
    const int e = e0 + gidx;

    const float4* kk = (const float4*)(kws + ((size_t)b * Lc + e) * HSc);
    const float4 kv0 = kk[l];
    const float4 kv1 = kk[4 + l];
    const float4 kv2 = kk[8 + l];
    const float4 kv3 = kk[12 + l];
    const float4 evq = ((const float4*)(Eqws + ((size_t)b * Lc + e) * OUTc))[l];
    const float4 evk = ((const float4*)(Ekws + ((size_t)b * Lc + e) * OUTc))[l];
    const float4 ev  = make_float4(evq.x + evk.x, evq.y + evk.y,
                                   evq.z + evk.z, evq.w + evk.w);

    float* ob = out + (size_t)b * Pc * OUTc;

    #pragma unroll 8
    for (int sl = 0; sl < 16; ++sl) {
        const int s = s0 + sl;
        const float4* qq = (const float4*)q_tile[sl];
        const float4 qv0 = qq[l];
        const float4 qv1 = qq[4 + l];
        const float4 qv2 = qq[8 + l];
        const float4 qv3 = qq[12 + l];

        float sc = qv0.x * kv0.x + qv0.y * kv0.y + qv0.z * kv0.z + qv0.w * kv0.w
                 + qv1.x * kv1.x + qv1.y * kv1.y + qv1.z * kv1.z + qv1.w * kv1.w
                 + qv2.x * kv2.x + qv2.y * kv2.y + qv2.z * kv2.z + qv2.w * kv2.w
                 + qv3.x * kv3.x + qv3.y * kv3.y + qv3.z * kv3.z + qv3.w * kv3.w;
        sc += __shfl_xor(sc, 1);
        sc += __shfl_xor(sc, 2);

        if (e >= s) {
            const float4 av = ((const float4*)A_tile[sl])[l];
            const int row = s * (2 * Lc + 1 - s) / 2 + (e - s);
            floatx4 r;
            r.x = av.x + ev.x + sc;
            r.y = av.y + ev.y + sc;
            r.z = av.z + ev.z + sc;
            r.w = av.w + ev.w + sc;
            __builtin_nontemporal_store(r, (floatx4*)(ob + (size_t)row * OUTc) + l);
        }
    }
}

extern "C" void kernel_launch(void* const* d_in, const int* in_sizes, int n_in,
                              void* d_out, int out_size, void* d_ws, size_t ws_size,
                              hipStream_t stream) {
    const float* x  = (const float*)d_in[0];
    const float* Wq = (const float*)d_in[1];
    const float* bq = (const float*)d_in[2];
    const float* Wk = (const float*)d_in[3];
    const float* bk = (const float*)d_in[4];
    const float* Wb = (const float*)d_in[5];
    const float* bb = (const float*)d_in[6];

    float* ws   = (float*)d_ws;
    float* qws  = ws;
    float* kws  = ws + 131072;
    float* Aws  = ws + 262144;
    float* Eqws = ws + 294912;
    float* Ekws = ws + 327680;

    qkae_kernel<<<dim3(256), dim3(256), 0, stream>>>(
        x, Wq, Wk, bq, bk, Wb, bb, qws, kws, Aws, Eqws, Ekws);
    pair_kernel<<<dim3(144, 4), dim3(256), 0, stream>>>(
        qws, kws, Aws, Eqws, Ekws, (float*)d_out);
}

// Round 7
// 93.757 us; speedup vs baseline: 1.7310x; 1.0051x over previous
//
#include <hip/hip_runtime.h>

// Problem constants (B, L, H, HS, OUT) = (4, 512, 768, 64, 16)
#define Bc   4
#define Lc   512
#define Hc   768
#define HSc  64
#define OUTc 16
#define Pc   131328   // L*(L+1)/2
#define NTOK 2048     // B*L

typedef float  floatx4 __attribute__((ext_vector_type(4)));
typedef short  bf16x8  __attribute__((ext_vector_type(8)));   // 8 bf16 in 4 VGPRs
typedef float  f32x4   __attribute__((ext_vector_type(4)));

// ws layout (floats): q@0 [131072], k@131072 [131072], A@262144 [32768],
//   Eq@294912 [32768], Ek@327680 [32768]
// ushorts @ float offset 360448: xbf [2048*768], Wt [128*768] (= concat(Wq|Wk)^T)

__device__ __forceinline__ unsigned short f2bf(float f) {
    unsigned int u = __float_as_uint(f);
    return (unsigned short)((u + 0x7FFFu + ((u >> 16) & 1u)) >> 16);   // RNE
}

// Prep (R0-proven): blocks 0..511 convert x to bf16; blocks 512..559 build
// Wt[n][k] bf16 (n<64 from Wq, n>=64 from Wk). Converts W ONCE instead of
// once per GEMM block (R2/R6 burned ~1000 VALU/lane on redundant f2bf -> the
// invariant ~20 us both rounds shared).
__global__ __launch_bounds__(256) void prep_kernel(
    const float* __restrict__ x, const float* __restrict__ Wq,
    const float* __restrict__ Wk,
    unsigned short* __restrict__ xbf, unsigned short* __restrict__ Wt)
{
    const int bx  = blockIdx.x;
    const int tid = threadIdx.x;
    if (bx < 512) {
        // 393216 float4 total = 512 blocks * 256 thr * 3
        const float4* xg = (const float4*)x;
        const int base = bx * 768;
        #pragma unroll
        for (int i = 0; i < 3; ++i) {
            const int idx = base + tid + i * 256;
            const float4 v = xg[idx];
            ushort4 o;
            o.x = f2bf(v.x); o.y = f2bf(v.y); o.z = f2bf(v.z); o.w = f2bf(v.w);
            ((ushort4*)xbf)[idx] = o;
        }
    } else {
        // W transpose tile: k rows [k0, k0+16) x 128 n -> Wt[n][k]
        const int k0 = (bx - 512) * 16;
        __shared__ unsigned short T[128][16];
        const int c  = tid & 127;           // n col
        const int kg = tid >> 7;            // 0..1
        const float* Wsrc = (c < 64) ? Wq : Wk;
        const int cc = c & 63;
        #pragma unroll
        for (int kk = 0; kk < 8; ++kk) {
            const int k = k0 + kg * 8 + kk;
            T[c][kg * 8 + kk] = f2bf(Wsrc[k * HSc + cc]);
        }
        __syncthreads();
        const int n = tid >> 1;
        const int h = tid & 1;
        const unsigned short* src = &T[n][h * 8];
        ushort4* dst = (ushort4*)(Wt + (size_t)n * Hc + k0 + h * 8);
        dst[0] = make_ushort4(src[0], src[1], src[2], src[3]);
        dst[1] = make_ushort4(src[4], src[5], src[6], src[7]);
    }
}

// QK-GEMM + A/Eq/Ek projection. Grid 256 x 256 thr (4 waves).
// Block bx: mb = bx>>1 (16-token tile), half = bx&1 (0 = q, 1 = k).
// GEMM phase = R0's proven gemm: a/b fragments stream from global bf16
// (xbf rows / Wt rows, 16B/lane), fully unrolled K-loop, no barriers, zero
// f2bf. Epilogue = R2's proven A/Eq/Ek projection from LDS.
// MFMA layouts (m89/m91): A[m=lane&15][k=quad*8+j]; B[k=quad*8+j][n=lane&15];
// D: col=lane&15, row=quad*4+reg.
__global__ __launch_bounds__(256) void qkae_kernel(
    const unsigned short* __restrict__ xbf, const unsigned short* __restrict__ Wt,
    const float* __restrict__ bq, const float* __restrict__ bk,
    const float* __restrict__ Wb, const float* __restrict__ bb,
    float* __restrict__ qws, float* __restrict__ kws,
    float* __restrict__ Aws, float* __restrict__ Eqws,
    float* __restrict__ Ekws)
{
    __shared__ float lw0[64 * OUTc];     // 4 KB
    __shared__ float lw1[64 * OUTc];     // 4 KB
    __shared__ float lqk[16][64];        // 4 KB

    const int tid  = threadIdx.x;
    const int mb   = blockIdx.x >> 1;
    const int half = blockIdx.x & 1;       // 0 = q, 1 = k
    const int m0   = mb * 16;

    // stage Wb slices (1024 floats each)
    if (half == 0) {
        #pragma unroll
        for (int i = 0; i < 4; ++i) {
            lw0[tid + i * 256] = Wb[tid + i * 256];           // rows 0..63   (A)
            lw1[tid + i * 256] = Wb[2048 + tid + i * 256];    // rows 128..191(Eq)
        }
    } else {
        #pragma unroll
        for (int i = 0; i < 4; ++i) {                          // rows 64..127 + 192..255
            lw0[tid + i * 256] = Wb[1024 + tid + i * 256] + Wb[3072 + tid + i * 256];
        }
    }

    const int w    = tid >> 6;
    const int lane = tid & 63;
    const int l15  = lane & 15;
    const int quad = lane >> 4;
    const int nq   = w * 16 + l15;           // output col 0..63 within this half

    const unsigned short* ap = xbf + (size_t)(m0 + l15) * Hc + quad * 8;
    const unsigned short* bp = Wt  + (size_t)(half * 64 + nq) * Hc + quad * 8;

    f32x4 acc = {0.f, 0.f, 0.f, 0.f};
    #pragma unroll
    for (int k0 = 0; k0 < Hc; k0 += 32) {
        const bf16x8 a = *(const bf16x8*)(ap + k0);
        const bf16x8 b = *(const bf16x8*)(bp + k0);
        acc = __builtin_amdgcn_mfma_f32_16x16x32_bf16(a, b, acc, 0, 0, 0);
    }

    const float bias = half ? bk[nq] : bq[nq];
    float* dst = half ? kws : qws;
    #pragma unroll
    for (int r = 0; r < 4; ++r) {
        const int t = quad * 4 + r;
        const float v = acc[r] + bias;
        dst[(size_t)(m0 + t) * HSc + nq] = v;
        lqk[t][nq] = v;
    }
    __syncthreads();

    // projection epilogue: 16 threads per token, one output col each
    const int t   = tid >> 4;        // token 0..15
    const int c   = tid & 15;
    const int tok = m0 + t;
    const float* row = lqk[t];
    if (half == 0) {
        float a = 0.f, eq = 0.f;
        #pragma unroll 8
        for (int h = 0; h < 64; ++h) {
            const float rv = row[h];
            a  += rv * lw0[h * OUTc + c];
            eq += rv * lw1[h * OUTc + c];
        }
        Aws[(size_t)tok * OUTc + c]  = a;
        Eqws[(size_t)tok * OUTc + c] = eq;
    } else {
        float ek = bb[c];
        #pragma unroll 8
        for (int h = 0; h < 64; ++h)
            ek += row[h] * lw0[h * OUTc + c];
        Ekws[(size_t)tok * OUTc + c] = ek;
    }
}

// Pair kernel: 16 s x 64 e tiles, only the 144 active upper-triangular tiles
// per batch (decoded in-kernel). Grid (144, 4): x = linear tile id, y = batch.
__global__ __launch_bounds__(256) void pair_kernel(
    const float* __restrict__ qws, const float* __restrict__ kws,
    const float* __restrict__ Aws, const float* __restrict__ Eqws,
    const float* __restrict__ Ekws,
    float* __restrict__ out)
{
    // decode linear tile id -> (i = s-tile 0..31, j = e-tile 0..7), j >= i>>2
    int n = blockIdx.x;
    int g = 0;
    int cnt = 32;                       // 4*(8-g)
    while (n >= cnt) { n -= cnt; ++g; cnt = 4 * (8 - g); }
    const int span = 8 - g;
    const int i = g * 4 + n / span;
    const int j = g + n % span;
    const int b = blockIdx.y;

    __shared__ alignas(16) float q_tile[16][64];
    __shared__ alignas(16) float A_tile[16][16];

    const int tid = threadIdx.x;
    const int s0 = i * 16;
    const int e0 = j * 64;

    {
        const int r = tid >> 4, c4 = tid & 15;
        ((float4*)q_tile[r])[c4] =
            ((const float4*)(qws + ((size_t)b * Lc + s0 + r) * HSc))[c4];
        if (tid < 64) {
            const int ra = tid >> 2, ca = tid & 3;
            ((float4*)A_tile[ra])[ca] =
                ((const float4*)(Aws + ((size_t)b * Lc + s0 + ra) * OUTc))[ca];
        }
    }
    __syncthreads();

    const int gidx = tid >> 2;
    const int l = tid & 3;
    const int e = e0 + gidx;

    const float4* kk = (const float4*)(kws + ((size_t)b * Lc + e) * HSc);
    const float4 kv0 = kk[l];
    const float4 kv1 = kk[4 + l];
    const float4 kv2 = kk[8 + l];
    const float4 kv3 = kk[12 + l];
    const float4 evq = ((const float4*)(Eqws + ((size_t)b * Lc + e) * OUTc))[l];
    const float4 evk = ((const float4*)(Ekws + ((size_t)b * Lc + e) * OUTc))[l];
    const float4 ev  = make_float4(evq.x + evk.x, evq.y + evk.y,
                                   evq.z + evk.z, evq.w + evk.w);

    float* ob = out + (size_t)b * Pc * OUTc;

    #pragma unroll 8
    for (int sl = 0; sl < 16; ++sl) {
        const int s = s0 + sl;
        const float4* qq = (const float4*)q_tile[sl];
        const float4 qv0 = qq[l];
        const float4 qv1 = qq[4 + l];
        const float4 qv2 = qq[8 + l];
        const float4 qv3 = qq[12 + l];

        float sc = qv0.x * kv0.x + qv0.y * kv0.y + qv0.z * kv0.z + qv0.w * kv0.w
                 + qv1.x * kv1.x + qv1.y * kv1.y + qv1.z * kv1.z + qv1.w * kv1.w
                 + qv2.x * kv2.x + qv2.y * kv2.y + qv2.z * kv2.z + qv2.w * kv2.w
                 + qv3.x * kv3.x + qv3.y * kv3.y + qv3.z * kv3.z + qv3.w * kv3.w;
        sc += __shfl_xor(sc, 1);
        sc += __shfl_xor(sc, 2);

        if (e >= s) {
            const float4 av = ((const float4*)A_tile[sl])[l];
            const int row = s * (2 * Lc + 1 - s) / 2 + (e - s);
            floatx4 r;
            r.x = av.x + ev.x + sc;
            r.y = av.y + ev.y + sc;
            r.z = av.z + ev.z + sc;
            r.w = av.w + ev.w + sc;
            __builtin_nontemporal_store(r, (floatx4*)(ob + (size_t)row * OUTc) + l);
        }
    }
}

extern "C" void kernel_launch(void* const* d_in, const int* in_sizes, int n_in,
                              void* d_out, int out_size, void* d_ws, size_t ws_size,
                              hipStream_t stream) {
    const float* x  = (const float*)d_in[0];
    const float* Wq = (const float*)d_in[1];
    const float* bq = (const float*)d_in[2];
    const float* Wk = (const float*)d_in[3];
    const float* bk = (const float*)d_in[4];
    const float* Wb = (const float*)d_in[5];
    const float* bb = (const float*)d_in[6];

    float* ws   = (float*)d_ws;
    float* qws  = ws;
    float* kws  = ws + 131072;
    float* Aws  = ws + 262144;
    float* Eqws = ws + 294912;
    float* Ekws = ws + 327680;
    unsigned short* xbf = (unsigned short*)(ws + 360448);
    unsigned short* Wt  = xbf + (size_t)NTOK * Hc;

    prep_kernel<<<dim3(560), dim3(256), 0, stream>>>(x, Wq, Wk, xbf, Wt);
    qkae_kernel<<<dim3(256), dim3(256), 0, stream>>>(
        xbf, Wt, bq, bk, Wb, bb, qws, kws, Aws, Eqws, Ekws);
    pair_kernel<<<dim3(144, 4), dim3(256), 0, stream>>>(
        qws, kws, Aws, Eqws, Ekws, (float*)d_out);
}